// Round 1
// baseline (16406.635 us; speedup 1.0000x reference)
//
#include <hip/hip_runtime.h>
#include <hip/hip_fp16.h>

// ---------------------------------------------------------------------------
// 2-layer LSTM (T=512, B=128, H=512) + linear head, persistent-kernel design.
//
// Partition: 4 batch-groups of 32. Per group:
//   layer1: 16 blocks x 32 h-cols (K=512)      -> XCDs 4..7 (blockIdx&7 >= 4)
//   layer2: 32 blocks x 16 h-cols (K=1024)     -> XCDs 0..3
// Layer1 streams h1(t) into a depth-16 ring consumed by layer2 (pipelined).
// Within a group: per-timestep release/acquire counters (device scope).
// 256 blocks x 256 threads, 64KB LDS -> 1 block/CU -> all blocks co-resident,
// so spin-waits cannot deadlock (no cooperative launch required).
// ---------------------------------------------------------------------------

#define HDIM   512
#define TSTEPS 512
#define BATCH  128
#define DIN    5
#define NGRP   4
#define MGRP   32
#define NB1    16
#define NB2    32
#define RING   16

// workspace byte offsets
#define OFF_W1 0u            // packed layer1 weights: 16 blocks * 128KB = 2MB
#define OFF_W2 2097152u      // packed layer2 weights: 32 blocks * 128KB = 4MB
#define OFF_H1 6291456u      // h1 ring: 4 * 16 * 32 * 512 fp16 = 2MB
#define OFF_H2 8388608u      // h2 ring: 4 * 2 * 32 * 512 fp16 = 256KB
#define OFF_C1 8650752u      // cnt1: 4 * 512 u32
#define OFF_C2 8658944u      // cnt2: 4 * 512 u32
#define WS_END 8667136u

typedef _Float16 half8 __attribute__((ext_vector_type(8)));
typedef float    floatx4 __attribute__((ext_vector_type(4)));

__device__ __forceinline__ float sigf(float v) { return 1.0f / (1.0f + __expf(-v)); }

__device__ __forceinline__ void spin_ge(unsigned* p, unsigned tgt) {
  while (__hip_atomic_load(p, __ATOMIC_ACQUIRE, __HIP_MEMORY_SCOPE_AGENT) < tgt)
    __builtin_amdgcn_s_sleep(1);
}

// ---------------------------------------------------------------------------
extern "C" __global__ void init_kernel(char* __restrict__ ws, float* __restrict__ out,
                                       const float* __restrict__ blin) {
  unsigned tid = blockIdx.x * 256u + threadIdx.x;
  unsigned nz = (WS_END - OFF_H1) / 16u;  // 148480 uint4s (rings + counters)
  if (tid < nz) ((uint4*)(ws + OFF_H1))[tid] = make_uint4(0, 0, 0, 0);
  if (tid < (unsigned)(BATCH * TSTEPS)) out[tid] = blin[0];
}

// Pack fp32 weights -> fp16 MFMA B-fragment layout.
// Layer1 slice j: [g(4)][h(2)][ks(16)][lane(64)][8]; B[k][n]=W[g*512+c][k],
//   c = j*32 + h*16 + (lane&15), k = ks*32 + (lane>>4)*8 + e.
// Layer2 slice j: [g(4)][ks(32)][lane(64)][8]; c = j*16 + (lane&15),
//   k' = ks*32 + (lane>>4)*8 + e; k'<512 -> W_ih2, else W_hh2[k'-512].
extern "C" __global__ void pack_kernel(const float* __restrict__ Whh1,
                                       const float* __restrict__ Wih2,
                                       const float* __restrict__ Whh2,
                                       char* __restrict__ ws) {
  unsigned tid = blockIdx.x * 256u + threadIdx.x;
  const float* src;
  char* dst;
  if (tid < 131072u) {
    unsigned lane = tid & 63u, ks = (tid >> 6) & 15u, h = (tid >> 10) & 1u,
             g = (tid >> 11) & 3u, j = tid >> 13;
    unsigned cg = j * 32u + h * 16u + (lane & 15u);
    unsigned row = g * 512u + cg;
    unsigned k0 = ks * 32u + (lane >> 4) * 8u;
    src = Whh1 + (size_t)row * 512u + k0;
    dst = ws + OFF_W1 + (size_t)tid * 16u;
  } else {
    unsigned t2 = tid - 131072u;
    if (t2 >= 262144u) return;
    unsigned lane = t2 & 63u, ks = (t2 >> 6) & 31u, g = (t2 >> 11) & 3u, j = t2 >> 13;
    unsigned cg = j * 16u + (lane & 15u);
    unsigned row = g * 512u + cg;
    unsigned kp = ks * 32u + (lane >> 4) * 8u;
    src = (kp < 512u) ? (Wih2 + (size_t)row * 512u + kp)
                      : (Whh2 + (size_t)row * 512u + (kp - 512u));
    dst = ws + OFF_W2 + (size_t)t2 * 16u;
  }
  float4 lo = ((const float4*)src)[0];
  float4 hi = ((const float4*)src)[1];
  _Float16 v[8] = {(_Float16)lo.x, (_Float16)lo.y, (_Float16)lo.z, (_Float16)lo.w,
                   (_Float16)hi.x, (_Float16)hi.y, (_Float16)hi.z, (_Float16)hi.w};
  *(uint4*)dst = *(const uint4*)v;
}

// ---------------------------------------------------------------------------
extern "C" __global__ __launch_bounds__(256) void lstm_persist(
    const float* __restrict__ x,
    const float* __restrict__ Wih1,
    const float* __restrict__ bih1, const float* __restrict__ bhh1,
    const float* __restrict__ bih2, const float* __restrict__ bhh2,
    const float* __restrict__ Wlin,
    float* __restrict__ out,
    char* __restrict__ ws) {
  __shared__ char smem[65536];

  const int blk = blockIdx.x;
  const int xcd = blk & 7;
  const int slot = blk >> 3;
  const int tid = threadIdx.x;
  const int wave = tid >> 6;
  const int lane = tid & 63;
  const int nlane = lane & 15;
  const int quad = lane >> 4;

  _Float16* h1ring = (_Float16*)(ws + OFF_H1);
  _Float16* h2ring = (_Float16*)(ws + OFF_H2);
  unsigned* cnt1 = (unsigned*)(ws + OFF_C1);
  unsigned* cnt2 = (unsigned*)(ws + OFF_C2);

  if (xcd >= NGRP) {
    // ------------------------------ layer 1 -------------------------------
    const int g = xcd - NGRP;
    const int j = slot;
    if (j >= NB1) return;
    const char* gW = ws + OFF_W1 + (size_t)j * 131072u;
    // LDS: first 48 tile-k rows (48KB) of weights; partials at 49152 (16KB)
    {
      const uint4* s = (const uint4*)gW;
      uint4* d = (uint4*)smem;
      for (int i = tid; i < 3072; i += 256) d[i] = s[i];
    }
    __syncthreads();
    floatx4* pbase = (floatx4*)(smem + 49152);

    const int hh = wave & 1;   // column half (16 cols)
    const int kh = wave >> 1;  // K half (256)
    const int cg = j * 32 + hh * 16 + nlane;
    unsigned* myc1 = cnt1 + g * TSTEPS;
    unsigned* myc2 = cnt2 + g * TSTEPS;
    _Float16* ring = h1ring + (size_t)g * (RING * MGRP * HDIM);

    float bias_r[4];
    float wih[4][5];
    for (int gg = 0; gg < 4; ++gg) {
      int row = gg * 512 + cg;
      bias_r[gg] = bih1[row] + bhh1[row];
      for (int k = 0; k < 5; ++k) wih[gg][k] = Wih1[row * 5 + k];
    }
    float cstate[2][4] = {};

    for (int t = 0; t < TSTEPS; ++t) {
      floatx4 acc[2][4];
      if (kh == 0) {
        // acc init = bias + x_t @ W_ih1^T  (fp32, K=5)
        for (int mt = 0; mt < 2; ++mt) {
          float xr[4][5];
          for (int r = 0; r < 4; ++r) {
            int b = g * MGRP + mt * 16 + quad * 4 + r;
            const float* xp = x + ((size_t)t * BATCH + b) * DIN;
            for (int k = 0; k < 5; ++k) xr[r][k] = xp[k];
          }
          for (int gg = 0; gg < 4; ++gg) {
            floatx4 a;
            for (int r = 0; r < 4; ++r) {
              float s = bias_r[gg];
              for (int k = 0; k < 5; ++k) s += xr[r][k] * wih[gg][k];
              a[r] = s;
            }
            acc[mt][gg] = a;
          }
        }
      } else {
        for (int mt = 0; mt < 2; ++mt)
          for (int gg = 0; gg < 4; ++gg) acc[mt][gg] = (floatx4){0.f, 0.f, 0.f, 0.f};
      }
      const _Float16* aprev = ring + (size_t)((t + RING - 1) % RING) * (MGRP * HDIM);
      const int ksbase = kh * 8;
      for (int ks = ksbase; ks < ksbase + 8; ++ks) {
        half8 a0 = *(const half8*)(aprev + (0 + nlane) * HDIM + ks * 32 + quad * 8);
        half8 a1 = *(const half8*)(aprev + (16 + nlane) * HDIM + ks * 32 + quad * 8);
        for (int gg = 0; gg < 4; ++gg) {
          int tk = (gg * 2 + hh) * 16 + ks;  // tile-k row (1KB each)
          half8 b = (tk < 48) ? *(const half8*)(smem + tk * 1024 + lane * 16)
                              : *(const half8*)(gW + tk * 1024 + lane * 16);
          acc[0][gg] = __builtin_amdgcn_mfma_f32_16x16x32_f16(a0, b, acc[0][gg], 0, 0, 0);
          acc[1][gg] = __builtin_amdgcn_mfma_f32_16x16x32_f16(a1, b, acc[1][gg], 0, 0, 0);
        }
      }
      if (kh == 1) {
        for (int mt = 0; mt < 2; ++mt)
          for (int gg = 0; gg < 4; ++gg)
            pbase[((wave - 2) * 8 + mt * 4 + gg) * 64 + lane] = acc[mt][gg];
      }
      __syncthreads();
      if (kh == 0) {
        for (int mt = 0; mt < 2; ++mt)
          for (int gg = 0; gg < 4; ++gg)
            acc[mt][gg] += pbase[(wave * 8 + mt * 4 + gg) * 64 + lane];
        if (t >= RING) spin_ge(&myc2[t - RING], NB2);  // ring back-pressure
        _Float16* hout = ring + (size_t)(t % RING) * (MGRP * HDIM);
        for (int mt = 0; mt < 2; ++mt) {
          for (int r = 0; r < 4; ++r) {
            float iv = acc[mt][0][r], fv = acc[mt][1][r];
            float gv = acc[mt][2][r], ov = acc[mt][3][r];
            float c = cstate[mt][r];
            float cn = sigf(fv) * c + sigf(iv) * tanhf(gv);
            float hn = sigf(ov) * tanhf(cn);
            cstate[mt][r] = cn;
            hout[(mt * 16 + quad * 4 + r) * HDIM + cg] = (_Float16)hn;
          }
        }
        __threadfence();
      }
      __syncthreads();
      if (tid == 0)
        __hip_atomic_fetch_add(&myc1[t], 1u, __ATOMIC_RELEASE, __HIP_MEMORY_SCOPE_AGENT);
      spin_ge(&myc1[t], NB1);
    }
  } else {
    // ------------------------------ layer 2 -------------------------------
    const int g = xcd;
    const int j = slot;
    const char* gW = ws + OFF_W2 + (size_t)j * 131072u;
    // LDS: first 40 tile-k rows (40KB); partials at 40960 (24KB)
    {
      const uint4* s = (const uint4*)gW;
      uint4* d = (uint4*)smem;
      for (int i = tid; i < 2560; i += 256) d[i] = s[i];
    }
    __syncthreads();
    floatx4* pbase = (floatx4*)(smem + 40960);

    const int cg = j * 16 + nlane;
    unsigned* myc1 = cnt1 + g * TSTEPS;
    unsigned* myc2 = cnt2 + g * TSTEPS;
    const _Float16* h1rd = h1ring + (size_t)g * (RING * MGRP * HDIM);
    _Float16* ring2 = h2ring + (size_t)g * (2 * MGRP * HDIM);

    float bias_r[4];
    for (int gg = 0; gg < 4; ++gg) {
      int row = gg * 512 + cg;
      bias_r[gg] = bih2[row] + bhh2[row];
    }
    const float wl = Wlin[cg];
    float cstate[2][4] = {};

    for (int t = 0; t < TSTEPS; ++t) {
      floatx4 acc[2][4];
      for (int mt = 0; mt < 2; ++mt)
        for (int gg = 0; gg < 4; ++gg)
          acc[mt][gg] = (wave == 0)
              ? (floatx4){bias_r[gg], bias_r[gg], bias_r[gg], bias_r[gg]}
              : (floatx4){0.f, 0.f, 0.f, 0.f};
      // waves 0,1 consume h1(t): wait for producer group
      if (wave < 2) spin_ge(&myc1[t], NB1);
      const _Float16* abase = (wave < 2)
          ? (h1rd + (size_t)(t % RING) * (MGRP * HDIM))
          : (ring2 + (size_t)((t + 1) & 1) * (MGRP * HDIM));
      const int koff = (wave < 2) ? 0 : 512;
      const int ksbase = wave * 8;
      for (int ks = ksbase; ks < ksbase + 8; ++ks) {
        const int kl = ks * 32 - koff;
        half8 a0 = *(const half8*)(abase + (0 + nlane) * HDIM + kl + quad * 8);
        half8 a1 = *(const half8*)(abase + (16 + nlane) * HDIM + kl + quad * 8);
        for (int gg = 0; gg < 4; ++gg) {
          int tk = gg * 32 + ks;
          half8 b = (tk < 40) ? *(const half8*)(smem + tk * 1024 + lane * 16)
                              : *(const half8*)(gW + tk * 1024 + lane * 16);
          acc[0][gg] = __builtin_amdgcn_mfma_f32_16x16x32_f16(a0, b, acc[0][gg], 0, 0, 0);
          acc[1][gg] = __builtin_amdgcn_mfma_f32_16x16x32_f16(a1, b, acc[1][gg], 0, 0, 0);
        }
      }
      if (wave > 0) {
        for (int mt = 0; mt < 2; ++mt)
          for (int gg = 0; gg < 4; ++gg)
            pbase[((wave - 1) * 8 + mt * 4 + gg) * 64 + lane] = acc[mt][gg];
      }
      __syncthreads();
      if (wave == 0) {
        for (int d = 0; d < 3; ++d)
          for (int mt = 0; mt < 2; ++mt)
            for (int gg = 0; gg < 4; ++gg)
              acc[mt][gg] += pbase[(d * 8 + mt * 4 + gg) * 64 + lane];
        _Float16* hout = ring2 + (size_t)(t & 1) * (MGRP * HDIM);
        float red[2][4];
        for (int mt = 0; mt < 2; ++mt) {
          for (int r = 0; r < 4; ++r) {
            float iv = acc[mt][0][r], fv = acc[mt][1][r];
            float gv = acc[mt][2][r], ov = acc[mt][3][r];
            float c = cstate[mt][r];
            float cn = sigf(fv) * c + sigf(iv) * tanhf(gv);
            float hn = sigf(ov) * tanhf(cn);
            cstate[mt][r] = cn;
            hout[(mt * 16 + quad * 4 + r) * HDIM + cg] = (_Float16)hn;
            red[mt][r] = wl * hn;
          }
        }
        for (int mt = 0; mt < 2; ++mt)
          for (int r = 0; r < 4; ++r) {
            float v = red[mt][r];
            v += __shfl_xor(v, 1, 64);
            v += __shfl_xor(v, 2, 64);
            v += __shfl_xor(v, 4, 64);
            v += __shfl_xor(v, 8, 64);
            red[mt][r] = v;
          }
        if (nlane == 0) {
          for (int mt = 0; mt < 2; ++mt)
            for (int r = 0; r < 4; ++r) {
              int b = g * MGRP + mt * 16 + quad * 4 + r;
              atomicAdd(out + (size_t)b * TSTEPS + t, red[mt][r]);
            }
        }
        __threadfence();
      }
      __syncthreads();
      if (tid == 0)
        __hip_atomic_fetch_add(&myc2[t], 1u, __ATOMIC_RELEASE, __HIP_MEMORY_SCOPE_AGENT);
      spin_ge(&myc2[t], NB2);
    }
  }
}

// ---------------------------------------------------------------------------
extern "C" void kernel_launch(void* const* d_in, const int* in_sizes, int n_in,
                              void* d_out, int out_size, void* d_ws, size_t ws_size,
                              hipStream_t stream) {
  const float* x    = (const float*)d_in[0];
  const float* Wih1 = (const float*)d_in[1];
  const float* Whh1 = (const float*)d_in[2];
  const float* bih1 = (const float*)d_in[3];
  const float* bhh1 = (const float*)d_in[4];
  const float* Wih2 = (const float*)d_in[5];
  const float* Whh2 = (const float*)d_in[6];
  const float* bih2 = (const float*)d_in[7];
  const float* bhh2 = (const float*)d_in[8];
  const float* Wlin = (const float*)d_in[9];
  const float* blin = (const float*)d_in[10];
  float* out = (float*)d_out;
  char* ws = (char*)d_ws;

  init_kernel<<<640, 256, 0, stream>>>(ws, out, blin);
  pack_kernel<<<1536, 256, 0, stream>>>(Whh1, Wih2, Whh2, ws);
  lstm_persist<<<256, 256, 0, stream>>>(x, Wih1, bih1, bhh1, bih2, bhh2, Wlin, out, ws);
}

// Round 2
// 3926.773 us; speedup vs baseline: 4.1781x; 4.1781x over previous
//
#include <hip/hip_runtime.h>
#include <hip/hip_fp16.h>

// ---------------------------------------------------------------------------
// 2-layer LSTM (T=512, B=128, H=512) + linear head, persistent-kernel design.
// Round 2: fence-free synchronization. All cross-block traffic uses relaxed
// agent-scope 8B atomic load/store (cache-bypassing -> LLC coherent point),
// so the per-XCD L2 is never invalidated and packed weights stay L2-warm.
// Polling is 1 lane per dependent wave (wave lockstep gives ordering) or
// tid0 + __syncthreads for end-of-step barriers.
// ---------------------------------------------------------------------------

#define HDIM   512
#define TSTEPS 512
#define BATCH  128
#define DIN    5
#define NGRP   4
#define MGRP   32
#define NB1    16
#define NB2    32
#define RING   16

#define OFF_W1 0u            // packed layer1 weights: 16 blocks * 128KB = 2MB
#define OFF_W2 2097152u      // packed layer2 weights: 32 blocks * 128KB = 4MB
#define OFF_H1 6291456u      // h1 ring: 4 * 16 * 32 * 512 fp16 = 2MB
#define OFF_H2 8388608u      // h2 ring: 4 * 2 * 32 * 512 fp16 = 256KB
#define OFF_C1 8650752u      // cnt1: 4 * 512 u32
#define OFF_C2 8658944u      // cnt2: 4 * 512 u32
#define WS_END 8667136u

#define L1_HALF 31   // LDS-resident b-rows per hh half (of 64) in layer1
#define L2_HALF 27   // LDS-resident b-rows per kh half (of 64) in layer2

typedef _Float16 half8 __attribute__((ext_vector_type(8)));
typedef float    floatx4 __attribute__((ext_vector_type(4)));

__device__ __forceinline__ float sigf(float v) { return 1.0f / (1.0f + __expf(-v)); }

// 16B A-fragment read from a ring buffer: two cache-bypassing 8B atomic loads.
__device__ __forceinline__ half8 ring_ld16(const _Float16* p) {
  union { unsigned long long u[2]; half8 h; } r;
  unsigned long long* q = (unsigned long long*)p;
  r.u[0] = __hip_atomic_load(q,     __ATOMIC_RELAXED, __HIP_MEMORY_SCOPE_AGENT);
  r.u[1] = __hip_atomic_load(q + 1, __ATOMIC_RELAXED, __HIP_MEMORY_SCOPE_AGENT);
  return r.h;
}
__device__ __forceinline__ void ring_st8(_Float16* p, unsigned long long v) {
  __hip_atomic_store((unsigned long long*)p, v, __ATOMIC_RELAXED, __HIP_MEMORY_SCOPE_AGENT);
}
__device__ __forceinline__ void spin_ge(unsigned* p, unsigned tgt) {
  while (__hip_atomic_load(p, __ATOMIC_RELAXED, __HIP_MEMORY_SCOPE_AGENT) < tgt)
    __builtin_amdgcn_s_sleep(1);
}

// ---------------------------------------------------------------------------
extern "C" __global__ void init_kernel(char* __restrict__ ws, float* __restrict__ out,
                                       const float* __restrict__ blin) {
  unsigned tid = blockIdx.x * 256u + threadIdx.x;
  unsigned nz = (WS_END - OFF_H1) / 16u;
  if (tid < nz) ((uint4*)(ws + OFF_H1))[tid] = make_uint4(0, 0, 0, 0);
  if (tid < (unsigned)(BATCH * TSTEPS)) out[tid] = blin[0];
}

// Pack fp32 weights -> fp16 MFMA B-fragment layout.
// Layer1 block j: rows ordered [h(2)][gate(4)][ks(16)], row = 64 lanes * 16B.
//   col c = j*32 + h*16 + (lane&15), k = ks*32 + (lane>>4)*8 + e.
// Layer2 block j: rows ordered [kh(2)][gate(4)][ksl(16)];
//   c = j*16 + (lane&15), k' = kh*512 + ksl*32 + (lane>>4)*8 + e;
//   k'<512 -> W_ih2[k'], else W_hh2[k'-512].
extern "C" __global__ void pack_kernel(const float* __restrict__ Whh1,
                                       const float* __restrict__ Wih2,
                                       const float* __restrict__ Whh2,
                                       char* __restrict__ ws) {
  unsigned tid = blockIdx.x * 256u + threadIdx.x;
  const float* src;
  char* dst;
  if (tid < 131072u) {
    unsigned lane = tid & 63u, ks = (tid >> 6) & 15u, gg = (tid >> 10) & 3u,
             h = (tid >> 12) & 1u, j = tid >> 13;
    unsigned cg = j * 32u + h * 16u + (lane & 15u);
    unsigned row = gg * 512u + cg;
    unsigned k0 = ks * 32u + (lane >> 4) * 8u;
    src = Whh1 + (size_t)row * 512u + k0;
    dst = ws + OFF_W1 + (size_t)tid * 16u;
  } else {
    unsigned t2 = tid - 131072u;
    if (t2 >= 262144u) return;
    unsigned lane = t2 & 63u, ksl = (t2 >> 6) & 15u, gg = (t2 >> 10) & 3u,
             kh = (t2 >> 12) & 1u, j = t2 >> 13;
    unsigned cg = j * 16u + (lane & 15u);
    unsigned row = gg * 512u + cg;
    unsigned kp = kh * 512u + ksl * 32u + (lane >> 4) * 8u;
    src = (kp < 512u) ? (Wih2 + (size_t)row * 512u + kp)
                      : (Whh2 + (size_t)row * 512u + (kp - 512u));
    dst = ws + OFF_W2 + (size_t)t2 * 16u;
  }
  float4 lo = ((const float4*)src)[0];
  float4 hi = ((const float4*)src)[1];
  _Float16 v[8] = {(_Float16)lo.x, (_Float16)lo.y, (_Float16)lo.z, (_Float16)lo.w,
                   (_Float16)hi.x, (_Float16)hi.y, (_Float16)hi.z, (_Float16)hi.w};
  *(uint4*)dst = *(const uint4*)v;
}

// ---------------------------------------------------------------------------
extern "C" __global__ __launch_bounds__(256) void lstm_persist(
    const float* __restrict__ x,
    const float* __restrict__ Wih1,
    const float* __restrict__ bih1, const float* __restrict__ bhh1,
    const float* __restrict__ bih2, const float* __restrict__ bhh2,
    const float* __restrict__ Wlin,
    float* __restrict__ out,
    char* __restrict__ ws) {
  __shared__ char smem[65536];

  const int blk = blockIdx.x;
  const int xcd = blk & 7;
  const int slot = blk >> 3;
  const int tid = threadIdx.x;
  const int wave = tid >> 6;
  const int lane = tid & 63;
  const int nlane = lane & 15;
  const int quad = lane >> 4;

  _Float16* h1ring = (_Float16*)(ws + OFF_H1);
  _Float16* h2ring = (_Float16*)(ws + OFF_H2);
  unsigned* cnt1 = (unsigned*)(ws + OFF_C1);
  unsigned* cnt2 = (unsigned*)(ws + OFF_C2);

  if (xcd >= NGRP) {
    // ------------------------------ layer 1 -------------------------------
    const int g = xcd - NGRP;
    const int j = slot;
    if (j >= NB1) return;
    const char* gW = ws + OFF_W1 + (size_t)j * 131072u;
    // LDS: 62 weight rows (31 per hh-half), h-tile 2KB at 63488
    {
      const uint4* s = (const uint4*)gW;
      uint4* d = (uint4*)smem;
      for (int i = tid; i < 62 * 64; i += 256) {
        int drow = i >> 6, c = i & 63;
        int srow = (drow < L1_HALF) ? drow : (64 + drow - L1_HALF);
        d[i] = s[srow * 64 + c];
      }
    }
    __syncthreads();
    _Float16* tile = (_Float16*)(smem + 63488);

    const int mt = wave >> 1;  // batch half (16 rows)
    const int hh = wave & 1;   // column half (16 cols)
    const int cg = j * 32 + hh * 16 + nlane;
    unsigned* myc1 = cnt1 + g * TSTEPS;
    unsigned* myc2 = cnt2 + g * TSTEPS;
    _Float16* ring = h1ring + (size_t)g * (RING * MGRP * HDIM);

    float bias_r[4], wih[4][5];
    for (int gg = 0; gg < 4; ++gg) {
      int row = gg * 512 + cg;
      bias_r[gg] = bih1[row] + bhh1[row];
      for (int k = 0; k < 5; ++k) wih[gg][k] = Wih1[row * 5 + k];
    }
    float cstate[4] = {};

    for (int t = 0; t < TSTEPS; ++t) {
      // acc init = bias + x_t @ W_ih1^T (fp32, K=5)
      float xr[4][5];
#pragma unroll
      for (int r = 0; r < 4; ++r) {
        int b = g * MGRP + mt * 16 + quad * 4 + r;
        const float* xp = x + ((size_t)t * BATCH + b) * DIN;
#pragma unroll
        for (int k = 0; k < 5; ++k) xr[r][k] = xp[k];
      }
      floatx4 acc[4];
#pragma unroll
      for (int gg = 0; gg < 4; ++gg) {
#pragma unroll
        for (int r = 0; r < 4; ++r) {
          float s = bias_r[gg];
#pragma unroll
          for (int k = 0; k < 5; ++k) s += xr[r][k] * wih[gg][k];
          acc[gg][r] = s;
        }
      }
      const _Float16* aprev =
          ring + (size_t)((t + RING - 1) % RING) * (MGRP * HDIM) + mt * 16 * HDIM;
#pragma unroll
      for (int ks = 0; ks < 16; ++ks) {
        half8 a = ring_ld16(aprev + nlane * HDIM + ks * 32 + quad * 8);
#pragma unroll
        for (int gg = 0; gg < 4; ++gg) {
          half8 b;
          if (gg * 16 + ks < L1_HALF)
            b = *(const half8*)(smem + ((hh * L1_HALF + gg * 16 + ks) * 64 + lane) * 16);
          else
            b = *(const half8*)(gW + (size_t)((hh * 64 + gg * 16 + ks) * 64 + lane) * 16);
          acc[gg] = __builtin_amdgcn_mfma_f32_16x16x32_f16(a, b, acc[gg], 0, 0, 0);
        }
      }
      // gates -> LDS transpose tile (32 rows x 32 cols fp16)
#pragma unroll
      for (int r = 0; r < 4; ++r) {
        float iv = acc[0][r], fv = acc[1][r], gv = acc[2][r], ov = acc[3][r];
        float cn = sigf(fv) * cstate[r] + sigf(iv) * tanhf(gv);
        float hn = sigf(ov) * tanhf(cn);
        cstate[r] = cn;
        tile[(mt * 16 + quad * 4 + r) * 32 + hh * 16 + nlane] = (_Float16)hn;
      }
      __syncthreads();
      // ring store: 256 threads x 8B, coalesced, write-through to LLC
      {
        _Float16* hout = ring + (size_t)(t % RING) * (MGRP * HDIM);
        unsigned long long v =
            *(const unsigned long long*)(tile + (tid >> 3) * 32 + (tid & 7) * 4);
        ring_st8(hout + (tid >> 3) * HDIM + j * 32 + (tid & 7) * 4, v);
      }
      __syncthreads();  // drains vmcnt: all stores visible before release
      if (tid == 0) {
        __hip_atomic_fetch_add(&myc1[t], 1u, __ATOMIC_RELAXED, __HIP_MEMORY_SCOPE_AGENT);
        spin_ge(&myc1[t], NB1);
        // amortized ring back-pressure: allows writes t+1..t+8 (lead <= 9 < RING)
        if ((t & 7) == 7 && t >= 15) spin_ge(&myc2[t - 8], NB2);
      }
      __syncthreads();
      __asm__ __volatile__("" ::: "memory");
    }
  } else {
    // ------------------------------ layer 2 -------------------------------
    const int g = xcd;
    const int j = slot;
    const char* gW = ws + OFF_W2 + (size_t)j * 131072u;
    // LDS: 54 weight rows (27 per kh-half), pbase 8KB at 55296, tile 1KB at 63488
    {
      const uint4* s = (const uint4*)gW;
      uint4* d = (uint4*)smem;
      for (int i = tid; i < 54 * 64; i += 256) {
        int drow = i >> 6, c = i & 63;
        int srow = (drow < L2_HALF) ? drow : (64 + drow - L2_HALF);
        d[i] = s[srow * 64 + c];
      }
    }
    __syncthreads();
    floatx4* pbase = (floatx4*)(smem + 55296);
    _Float16* tile2 = (_Float16*)(smem + 63488);

    const int kh = wave & 1;   // K half: 0 -> h1(t) (W_ih2), 1 -> h2(t-1) (W_hh2)
    const int mt = wave >> 1;  // batch half
    const int cg = j * 16 + nlane;
    unsigned* myc1 = cnt1 + g * TSTEPS;
    unsigned* myc2 = cnt2 + g * TSTEPS;
    const _Float16* h1rd = h1ring + (size_t)g * (RING * MGRP * HDIM);
    _Float16* ring2 = h2ring + (size_t)g * (2 * MGRP * HDIM);

    float bias_r[4];
    for (int gg = 0; gg < 4; ++gg) {
      int row = gg * 512 + cg;
      bias_r[gg] = bih2[row] + bhh2[row];
    }
    const float wl = Wlin[cg];
    float cstate[4] = {};

    for (int t = 0; t < TSTEPS; ++t) {
      floatx4 acc[4];
#pragma unroll
      for (int gg = 0; gg < 4; ++gg)
        acc[gg] = (kh == 0)
            ? (floatx4){bias_r[gg], bias_r[gg], bias_r[gg], bias_r[gg]}
            : (floatx4){0.f, 0.f, 0.f, 0.f};
      if (kh == 0) {
        if (lane == 0) spin_ge(myc1 + t, NB1);  // wave-lockstep: whole wave waits
        __asm__ __volatile__("" ::: "memory");
      }
      const _Float16* abase = (kh == 0)
          ? h1rd + (size_t)(t % RING) * (MGRP * HDIM) + mt * 16 * HDIM
          : ring2 + (size_t)((t + 1) & 1) * (MGRP * HDIM) + mt * 16 * HDIM;
#pragma unroll
      for (int ksl = 0; ksl < 16; ++ksl) {
        half8 a = ring_ld16(abase + nlane * HDIM + ksl * 32 + quad * 8);
#pragma unroll
        for (int gg = 0; gg < 4; ++gg) {
          half8 b;
          if (gg * 16 + ksl < L2_HALF)
            b = *(const half8*)(smem + ((kh * L2_HALF + gg * 16 + ksl) * 64 + lane) * 16);
          else
            b = *(const half8*)(gW + (size_t)((kh * 64 + gg * 16 + ksl) * 64 + lane) * 16);
          acc[gg] = __builtin_amdgcn_mfma_f32_16x16x32_f16(a, b, acc[gg], 0, 0, 0);
        }
      }
      if (kh == 1) {
#pragma unroll
        for (int gg = 0; gg < 4; ++gg) pbase[(mt * 4 + gg) * 64 + lane] = acc[gg];
      }
      __syncthreads();
      if (kh == 0) {
#pragma unroll
        for (int gg = 0; gg < 4; ++gg) acc[gg] += pbase[(mt * 4 + gg) * 64 + lane];
        float red[4];
#pragma unroll
        for (int r = 0; r < 4; ++r) {
          float iv = acc[0][r], fv = acc[1][r], gv = acc[2][r], ov = acc[3][r];
          float cn = sigf(fv) * cstate[r] + sigf(iv) * tanhf(gv);
          float hn = sigf(ov) * tanhf(cn);
          cstate[r] = cn;
          tile2[(mt * 16 + quad * 4 + r) * 16 + nlane] = (_Float16)hn;
          red[r] = wl * hn;
        }
#pragma unroll
        for (int r = 0; r < 4; ++r) {
          float v = red[r];
          v += __shfl_xor(v, 1, 64);
          v += __shfl_xor(v, 2, 64);
          v += __shfl_xor(v, 4, 64);
          v += __shfl_xor(v, 8, 64);
          red[r] = v;
        }
        if (nlane == 0) {
#pragma unroll
          for (int r = 0; r < 4; ++r) {
            int b = g * MGRP + mt * 16 + quad * 4 + r;
            atomicAdd(out + (size_t)b * TSTEPS + t, red[r]);
          }
        }
      }
      __syncthreads();
      if (tid < 128) {
        unsigned long long v =
            *(const unsigned long long*)(tile2 + (tid >> 2) * 16 + (tid & 3) * 4);
        ring_st8(ring2 + (size_t)(t & 1) * (MGRP * HDIM) + (tid >> 2) * HDIM +
                     j * 16 + (tid & 3) * 4, v);
      }
      __syncthreads();  // drains vmcnt before release
      if (tid == 0) {
        __hip_atomic_fetch_add(&myc2[t], 1u, __ATOMIC_RELAXED, __HIP_MEMORY_SCOPE_AGENT);
        spin_ge(&myc2[t], NB2);
      }
      __syncthreads();
      __asm__ __volatile__("" ::: "memory");
    }
  }
}

// ---------------------------------------------------------------------------
extern "C" void kernel_launch(void* const* d_in, const int* in_sizes, int n_in,
                              void* d_out, int out_size, void* d_ws, size_t ws_size,
                              hipStream_t stream) {
  const float* x    = (const float*)d_in[0];
  const float* Wih1 = (const float*)d_in[1];
  const float* Whh1 = (const float*)d_in[2];
  const float* bih1 = (const float*)d_in[3];
  const float* bhh1 = (const float*)d_in[4];
  const float* Wih2 = (const float*)d_in[5];
  const float* Whh2 = (const float*)d_in[6];
  const float* bih2 = (const float*)d_in[7];
  const float* bhh2 = (const float*)d_in[8];
  const float* Wlin = (const float*)d_in[9];
  const float* blin = (const float*)d_in[10];
  float* out = (float*)d_out;
  char* ws = (char*)d_ws;

  init_kernel<<<640, 256, 0, stream>>>(ws, out, blin);
  pack_kernel<<<1536, 256, 0, stream>>>(Whh1, Wih2, Whh2, ws);
  lstm_persist<<<256, 256, 0, stream>>>(x, Wih1, bih1, bhh1, bih2, bhh2, Wlin, out, ws);
}